// Round 1
// 375.482 us; speedup vs baseline: 1.0374x; 1.0374x over previous
//
#include <hip/hip_runtime.h>
#include <math.h>

constexpr int BLK = 256;
constexpr int NBLKA = 256;     // phase-A blocks for edge bucketing

static inline int cdiv(long a, long b) { return (int)((a + b - 1) / b); }

typedef __attribute__((ext_vector_type(8))) short short8;
typedef __attribute__((ext_vector_type(4))) float floatx4;

// ---------------- bf16 helpers (RNE) -----------------------------------------
__device__ __forceinline__ unsigned short f2bf(float f) {
    unsigned u = __float_as_uint(f);
    unsigned r = u + 0x7fffu + ((u >> 16) & 1u);
    return (unsigned short)(r >> 16);
}
__device__ __forceinline__ float bf2f(unsigned short s) {
    return __uint_as_float(((unsigned)s) << 16);
}

// ============== CSR build via 2-phase bucket sort (NO global atomics) ========
// Bucket b covers nodes [b*256, b*256+256). histg layout: [z*nbkt + b].

__global__ void histA_k(const int* __restrict__ dst, int* __restrict__ histg,
                        int E, int nbkt, int chunk) {
    __shared__ int h[256];
    int tid = threadIdx.x, z = blockIdx.x;
    h[tid] = 0;
    __syncthreads();
    int e0 = z * chunk, e1 = min(E, e0 + chunk);
    for (int e = e0 + tid; e < e1; e += BLK) atomicAdd(&h[dst[e] >> 8], 1);
    __syncthreads();
    if (tid < nbkt) histg[z * nbkt + tid] = h[tid];
}

__global__ void bucket_scan_k(const int* __restrict__ histg, int* __restrict__ bucket_base,
                              int nbkt, int E, int* __restrict__ gs, int* __restrict__ ge,
                              int G, float* __restrict__ bnstats) {
    __shared__ int s[BLK];
    int t = threadIdx.x;
    int v = 0;
    if (t < nbkt)
        for (int z = 0; z < NBLKA; ++z) v += histg[z * nbkt + t];
    s[t] = v;
    __syncthreads();
    for (int o = 1; o < BLK; o <<= 1) {
        int tv = (t >= o) ? s[t - o] : 0;
        __syncthreads();
        s[t] += tv;
        __syncthreads();
    }
    if (t < nbkt) bucket_base[t] = s[t] - v;
    if (t == 0) bucket_base[nbkt] = E;
    for (int i = t; i < G; i += BLK) { gs[i] = 0x7fffffff; ge[i] = -1; }
    for (int i = t; i < 1024; i += BLK) bnstats[i] = 0.f;   // 4 layers x 256
}

__global__ void blk_scan_k(int* __restrict__ histg, const int* __restrict__ bucket_base,
                           int nbkt) {
    __shared__ int s[BLK];
    int t = threadIdx.x, b = blockIdx.x;
    int v = histg[t * nbkt + b];
    s[t] = v;
    __syncthreads();
    for (int o = 1; o < BLK; o <<= 1) {
        int tv = (t >= o) ? s[t - o] : 0;
        __syncthreads();
        s[t] += tv;
        __syncthreads();
    }
    histg[t * nbkt + b] = bucket_base[b] + s[t] - v;
}

__global__ void scatterA_k(const int* __restrict__ src, const int* __restrict__ dst,
                           const int* __restrict__ histg, unsigned* __restrict__ ebkt,
                           int E, int nbkt, int chunk) {
    __shared__ int cur[256];
    int tid = threadIdx.x, z = blockIdx.x;
    if (tid < nbkt) cur[tid] = histg[z * nbkt + tid];
    __syncthreads();
    int e0 = z * chunk, e1 = min(E, e0 + chunk);
    for (int e = e0 + tid; e < e1; e += BLK) {
        int d = dst[e];
        int b = d >> 8;
        int pos = atomicAdd(&cur[b], 1);
        ebkt[pos] = ((unsigned)(d & 255) << 16) | (unsigned)src[e];
    }
}

// B: per-bucket CSR finalize (degrees->scan->self-loop->fill) + graph ranges.
__global__ void csrB_k(const unsigned* __restrict__ ebkt, const int* __restrict__ bucket_base,
                       int* __restrict__ off, unsigned short* __restrict__ csr,
                       const int* __restrict__ batch, int* __restrict__ gs,
                       int* __restrict__ ge, int N, int E, int nbkt) {
    __shared__ int dg[256];
    __shared__ int sc[256];
    int t = threadIdx.x, b = blockIdx.x;
    int n0 = b << 8;
    int cnt = min(256, N - n0);
    dg[t] = (t < cnt) ? 1 : 0;                     // self-loop
    __syncthreads();
    int e0 = bucket_base[b], e1 = bucket_base[b + 1];
    for (int e = e0 + t; e < e1; e += BLK) atomicAdd(&dg[ebkt[e] >> 16], 1);
    __syncthreads();
    int d = dg[t];
    sc[t] = d;
    __syncthreads();
    for (int o = 1; o < BLK; o <<= 1) {
        int tv = (t >= o) ? sc[t - o] : 0;
        __syncthreads();
        sc[t] += tv;
        __syncthreads();
    }
    int loff = sc[t] - d;                          // exclusive
    int csrbase = e0 + n0;                         // n0 self-loops precede bucket
    if (t < cnt) {
        off[n0 + t] = csrbase + loff;
        csr[csrbase + loff] = (unsigned short)(n0 + t);   // self-loop slot
        dg[t] = loff + 1;                          // cursor
    }
    if (b == nbkt - 1 && t == 0) off[N] = E + N;
    // graph ranges (batch sorted): boundary detection, this grid covers N.
    int n = n0 + t;
    if (n < N) {
        int bb = batch[n];
        if (n == 0) gs[bb] = 0;
        else {
            int pb = batch[n - 1];
            if (pb != bb) { gs[bb] = n; ge[pb] = n - 1; }
        }
        if (n == N - 1) ge[bb] = N - 1;
    }
    __syncthreads();
    for (int e = e0 + t; e < e1; e += BLK) {
        unsigned w = ebkt[e];
        int pos = atomicAdd(&dg[w >> 16], 1);
        csr[csrbase + pos] = (unsigned short)(w & 0xffff);
    }
}

// ---------------- self-contained MFMA GEMM (prep fused in prologue) -----------
template <int K, int NOUT, bool AFP32, bool HASBN>
__launch_bounds__(256)
__global__ void gemm_fused(const void* __restrict__ av, const float* __restrict__ W,
                           const float* __restrict__ a_s, const float* __restrict__ a_d,
                           const float* __restrict__ bnst, const float* __restrict__ g_prev,
                           const float* __restrict__ be_prev, float invN,
                           unsigned short* __restrict__ hb,
                           float* __restrict__ asrc, float* __restrict__ adst, int N) {
    constexpr int KF = K / 32;
    __shared__ float s_sca[K], s_scc[K], s_rs[K], s_rd[K], s_bd[2];
    int tid = threadIdx.x;
    if (tid < K) {
        float a = 1.f, c = 0.f;
        if (HASBN) {
            float mu = bnst[tid] * invN;
            float var = bnst[128 + tid] * invN - mu * mu;
            a = g_prev[tid] * rsqrtf(var + 1e-5f);
            c = be_prev[tid] - mu * a;
        }
        s_sca[tid] = a; s_scc[tid] = c;
    }
    __syncthreads();
    const bool dots = (blockIdx.y == 0);
    if (dots) {                             // block-uniform branch: syncs legal
        if (tid < K) {
            const float* wr = W + (long)tid * NOUT;
            float rs = 0.f, rd = 0.f;
            for (int f = 0; f < NOUT; ++f) {
                float w = wr[f];
                rs += w * a_s[f];
                rd += w * a_d[f];
            }
            s_rs[tid] = rs; s_rd[tid] = rd;
        }
        __syncthreads();
        if (tid < 2) {
            const float* r = tid ? s_rd : s_rs;
            float b = 0.f;
            for (int k = 0; k < K; ++k) b += s_scc[k] * r[k];
            s_bd[tid] = b;
        }
        __syncthreads();
    }

    int wave = tid >> 6;
    int lane = tid & 63;
    int quad = lane >> 4;
    int r16 = lane & 15;
    int col = blockIdx.y * 16 + r16;

    // ---- B fragment (BN-scaled inline) + bias[col] partial ----
    short8 bfr[KF];
    float biasp = 0.f;
#pragma unroll
    for (int kk = 0; kk < KF; ++kk) {
        short8 b;
#pragma unroll
        for (int j = 0; j < 8; ++j) {
            int k = kk * 32 + quad * 8 + j;
            float w = W[(long)k * NOUT + col];
            b[j] = (short)f2bf(s_sca[k] * w);
            biasp += s_scc[k] * w;
        }
        bfr[kk] = b;
    }
    biasp += __shfl_xor(biasp, 16, 64);
    biasp += __shfl_xor(biasp, 32, 64);

    int blockbase = blockIdx.x * 128;
#pragma unroll
    for (int rt = 0; rt < 2; ++rt) {
        int tilebase = blockbase + wave * 32 + rt * 16;
        if (tilebase >= N) break;                       // wave-uniform
        int arow = min(tilebase + r16, N - 1);
        short8 afr[KF];
        if (AFP32) {
            const float* xr = (const float*)av + (long)arow * K;
#pragma unroll
            for (int kk = 0; kk < KF; ++kk) {
                float4 x0 = *(const float4*)(xr + kk * 32 + quad * 8);
                float4 x1 = *(const float4*)(xr + kk * 32 + quad * 8 + 4);
                short8 a;
                a[0] = (short)f2bf(x0.x); a[1] = (short)f2bf(x0.y);
                a[2] = (short)f2bf(x0.z); a[3] = (short)f2bf(x0.w);
                a[4] = (short)f2bf(x1.x); a[5] = (short)f2bf(x1.y);
                a[6] = (short)f2bf(x1.z); a[7] = (short)f2bf(x1.w);
                afr[kk] = a;
            }
        } else {
            const unsigned short* hr = (const unsigned short*)av + (long)arow * K;
#pragma unroll
            for (int kk = 0; kk < KF; ++kk)
                afr[kk] = *(const short8*)(hr + kk * 32 + quad * 8);
        }
        floatx4 acc = {0.f, 0.f, 0.f, 0.f};
#pragma unroll
        for (int kk = 0; kk < KF; ++kk)
            acc = __builtin_amdgcn_mfma_f32_16x16x32_bf16(afr[kk], bfr[kk], acc, 0, 0, 0);
#pragma unroll
        for (int rr = 0; rr < 4; ++rr) {
            int srow = tilebase + quad * 4 + rr;
            if (srow < N) hb[(long)srow * NOUT + col] = f2bf(acc[rr] + biasp);
        }
        if (dots) {
            float ds = 0.f, dd = 0.f;
#pragma unroll
            for (int kk = 0; kk < KF; ++kk) {
                int kb = kk * 32 + quad * 8;
#pragma unroll
                for (int j = 0; j < 8; ++j) {
                    int k = kb + j;
                    float a = bf2f((unsigned short)afr[kk][j]) * s_sca[k];
                    ds += a * s_rs[k];
                    dd += a * s_rd[k];
                }
            }
            ds += __shfl_xor(ds, 16, 64); ds += __shfl_xor(ds, 32, 64);
            dd += __shfl_xor(dd, 16, 64); dd += __shfl_xor(dd, 32, 64);
            int drow = tilebase + r16;
            if (quad == 0 && drow < N) {
                asrc[drow] = ds + s_bd[0];
                adst[drow] = dd + s_bd[1];
            }
        }
    }
}

// ---------------- fused softmax + gather + bias + leaky(0.01), bf16 out ------
// SINGLE-PASS online softmax: since weights are computed as exp(e) with no
// max-subtraction anyway (numerically safe here: |e| is O(1)), we accumulate
// unnormalized acc += w*h[s] and sum += w together, then scale by 1/sum at the
// end. Each of the TPN lanes of a node-group computes w redundantly (cheap
// VALU) which makes csr[p]/asrc[s] same-address broadcast loads and removes
// ALL __shfl broadcasts, the two-pass structure, the register weight cache,
// and the deg>CW recompute divergence of the previous version.
template <int DOUT>
__global__ void gather_fused(const int* __restrict__ off,
                             const unsigned short* __restrict__ csr,
                             const float* __restrict__ asrc, const float* __restrict__ adst,
                             const unsigned short* __restrict__ hb,
                             const float* __restrict__ b,
                             unsigned short* __restrict__ out, int N) {
    constexpr int TPN = DOUT / 8;
    int t = blockIdx.x * blockDim.x + threadIdx.x;
    int d = t / TPN;
    if (d >= N) return;
    int l = t % TPN;
    int p0 = off[d], p1 = off[d + 1];
    float ad = adst[d];
    const int f0 = l * 8;

    float acc[8];
#pragma unroll
    for (int i = 0; i < 8; ++i) acc[i] = 0.f;
    float sum = 0.f;

#pragma unroll 2
    for (int p = p0; p < p1; ++p) {
        int s = csr[p];                           // broadcast across group
        float e = asrc[s] + ad;                   // broadcast load
        e = e > 0.f ? e : 0.2f * e;               // leaky_relu(0.2)
        float w = __expf(e);
        sum += w;
        const uint4 hv = *(const uint4*)(hb + (long)s * DOUT + f0);
        acc[0] += w * bf2f((unsigned short)(hv.x & 0xffff));
        acc[1] += w * bf2f((unsigned short)(hv.x >> 16));
        acc[2] += w * bf2f((unsigned short)(hv.y & 0xffff));
        acc[3] += w * bf2f((unsigned short)(hv.y >> 16));
        acc[4] += w * bf2f((unsigned short)(hv.z & 0xffff));
        acc[5] += w * bf2f((unsigned short)(hv.z >> 16));
        acc[6] += w * bf2f((unsigned short)(hv.w & 0xffff));
        acc[7] += w * bf2f((unsigned short)(hv.w >> 16));
    }
    float inv = 1.f / sum;                        // self-loop guarantees sum > 0

    float4 b0 = *(const float4*)(b + f0);
    float4 b1 = *(const float4*)(b + f0 + 4);
    float bb[8] = {b0.x, b0.y, b0.z, b0.w, b1.x, b1.y, b1.z, b1.w};
    ushort4 o0, o1;
#pragma unroll
    for (int i = 0; i < 8; ++i) {
        float v = acc[i] * inv + bb[i];
        v = v > 0.f ? v : 0.01f * v;             // leaky_relu(0.01)
        unsigned short hv = f2bf(v);
        if (i < 4) ((unsigned short*)&o0)[i] = hv;
        else       ((unsigned short*)&o1)[i - 4] = hv;
    }
    *(ushort4*)(out + (long)d * DOUT + f0) = o0;
    *(ushort4*)(out + (long)d * DOUT + f0 + 4) = o1;
}

// ---------------- BN statistics over bf16 activations (120-block pass) -------
template <int DOUT>
__global__ void stats_k(const unsigned short* __restrict__ y, float* __restrict__ bnsum,
                        float* __restrict__ bnsq, int N) {
    constexpr int QPR = DOUT / 8;
    __shared__ float ssum[DOUT];
    __shared__ float ssq[DOUT];
    for (int i = threadIdx.x; i < DOUT; i += blockDim.x) { ssum[i] = 0.f; ssq[i] = 0.f; }
    __syncthreads();
    long total = (long)N * QPR;
    long stride = (long)gridDim.x * blockDim.x;     // multiple of QPR
    long t0 = (long)blockIdx.x * blockDim.x + threadIdx.x;
    int f0 = (int)(t0 % QPR) * 8;
    float ls[8], lq[8];
#pragma unroll
    for (int i = 0; i < 8; ++i) { ls[i] = 0.f; lq[i] = 0.f; }
    for (long t = t0; t < total; t += stride) {
        uint4 hv = *(const uint4*)(y + t * 8);
        unsigned vv[4] = {hv.x, hv.y, hv.z, hv.w};
#pragma unroll
        for (int q = 0; q < 4; ++q) {
            float v0 = bf2f((unsigned short)(vv[q] & 0xffff));
            float v1 = bf2f((unsigned short)(vv[q] >> 16));
            ls[2 * q] += v0;     lq[2 * q] += v0 * v0;
            ls[2 * q + 1] += v1; lq[2 * q + 1] += v1 * v1;
        }
    }
#pragma unroll
    for (int i = 0; i < 8; ++i) {
        atomicAdd(&ssum[f0 + i], ls[i]);
        atomicAdd(&ssq[f0 + i], lq[i]);
    }
    __syncthreads();
    for (int i = threadIdx.x; i < DOUT; i += blockDim.x) {
        atomicAdd(&bnsum[i], ssum[i]);
        atomicAdd(&bnsq[i], ssq[i]);
    }
}

// ---------------- pool (with inline final BN) + MLP head, fused --------------
__global__ void pool_head_k(const unsigned short* __restrict__ h, const int* __restrict__ gs,
                            const int* __restrict__ ge, const float* __restrict__ bnst,
                            const float* __restrict__ g4, const float* __restrict__ be4,
                            float invN, const float* __restrict__ Wf,
                            const float* __restrict__ bf, const float* __restrict__ Wc,
                            const float* __restrict__ bc, float* __restrict__ out) {
    int g = blockIdx.x;
    int t = threadIdx.x;                          // 64 threads
    __shared__ float p[64];
    __shared__ float z[32];
    float mu = bnst[t] * invN;
    float var = bnst[128 + t] * invN - mu * mu;
    float a = g4[t] * rsqrtf(var + 1e-5f);
    float c = be4[t] - mu * a;
    int s0 = gs[g], s1 = ge[g];
    float acc = 0.f, cnt = 0.f;
    if (s0 <= s1) {
        cnt = (float)(s1 - s0 + 1);
        for (int n = s0; n <= s1; ++n) acc += bf2f(h[(long)n * 64 + t]);
    }
    p[t] = a * acc + cnt * c;
    __syncthreads();
    if (t < 32) {
        float zacc = bf[t];
#pragma unroll
        for (int f = 0; f < 64; ++f) zacc += p[f] * Wf[f * 32 + t];
        z[t] = zacc > 0.f ? zacc : 0.01f * zacc;
    }
    __syncthreads();
    if (t < 8) {
        float oacc = bc[t];
#pragma unroll
        for (int o = 0; o < 32; ++o) oacc += z[o] * Wc[o * 8 + t];
        out[(long)g * 8 + t] = 1.f / (1.f + __expf(-oacc));
    }
}

extern "C" void kernel_launch(void* const* d_in, const int* in_sizes, int n_in,
                              void* d_out, int out_size, void* d_ws, size_t ws_size,
                              hipStream_t stream) {
    const float* x   = (const float*)d_in[0];
    const int* ei    = (const int*)d_in[1];
    const int* batch = (const int*)d_in[2];
    const int N  = in_sizes[2];
    const int E  = in_sizes[1] / 2;
    const int ET = E + N;
    const int G  = out_size / 8;
    const int* src = ei;
    const int* dst = ei + E;

    const float *W[4], *as_[4], *ad_[4], *bb[4], *gg[4], *be_[4];
    for (int i = 0; i < 4; ++i) {
        W[i]   = (const float*)d_in[3 + 6 * i];
        as_[i] = (const float*)d_in[4 + 6 * i];
        ad_[i] = (const float*)d_in[5 + 6 * i];
        bb[i]  = (const float*)d_in[6 + 6 * i];
        gg[i]  = (const float*)d_in[7 + 6 * i];
        be_[i] = (const float*)d_in[8 + 6 * i];
    }
    const float* Wf = (const float*)d_in[27];
    const float* bfp = (const float*)d_in[28];
    const float* Wc = (const float*)d_in[29];
    const float* bc = (const float*)d_in[30];

    float* ws = (float*)d_ws;
    long off_ = 0;
    auto alloc = [&](long nelem) { float* p = ws + off_; off_ += (nelem + 3) & ~3L; return p; };
    unsigned short* h2a = (unsigned short*)alloc((long)N * 64);  // N x 128 bf16
    unsigned short* h2b = (unsigned short*)alloc((long)N * 64);
    unsigned short* hb  = (unsigned short*)alloc((long)N * 64);
    float* asrc     = alloc(N);
    float* adst     = alloc(N);
    float* bnstats  = alloc(4 * 256);       // per-layer: sum[128] | sq[128]
    unsigned* ebkt  = (unsigned*)alloc(E);
    int* histg      = (int*)alloc((long)NBLKA * 256);
    int* bucket_base = (int*)alloc(260);
    int* off        = (int*)alloc(N + 1);
    unsigned short* csr = (unsigned short*)alloc(ET / 2 + 2);
    int* gs         = (int*)alloc(G);
    int* ge         = (int*)alloc(G);
    (void)ws_size; (void)n_in;

    const int nbkt = cdiv(N, 256);          // 196
    const int chunk = cdiv(E, NBLKA);
    const float invN = 1.f / (float)N;

    // ---- CSR build (bucket sort, no global atomics) + graph ranges ----
    histA_k<<<NBLKA, BLK, 0, stream>>>(dst, histg, E, nbkt, chunk);
    bucket_scan_k<<<1, BLK, 0, stream>>>(histg, bucket_base, nbkt, E, gs, ge, G, bnstats);
    blk_scan_k<<<nbkt, BLK, 0, stream>>>(histg, bucket_base, nbkt);
    scatterA_k<<<NBLKA, BLK, 0, stream>>>(src, dst, histg, ebkt, E, nbkt, chunk);
    csrB_k<<<nbkt, BLK, 0, stream>>>(ebkt, bucket_base, off, csr, batch, gs, ge, N, E, nbkt);

#define LAYER(i, DIN, DOUT, AFP32, HASBN, INP, OUTP, BNPREV, GPREV, BEPREV)               \
    do {                                                                                  \
        gemm_fused<DIN, DOUT, AFP32, HASBN>                                               \
            <<<dim3(cdiv(N, 128), DOUT / 16), 256, 0, stream>>>(                          \
                INP, W[i], as_[i], ad_[i], BNPREV, GPREV, BEPREV, invN,                   \
                hb, asrc, adst, N);                                                       \
        gather_fused<DOUT><<<cdiv((long)N * (DOUT / 8), BLK), BLK, 0, stream>>>(          \
            off, csr, asrc, adst, hb, bb[i], OUTP, N);                                    \
        stats_k<DOUT><<<120, BLK, 0, stream>>>(OUTP, bnstats + i * 256,                   \
                                               bnstats + i * 256 + 128, N);               \
    } while (0)

    LAYER(0, 128, 32, true, false, x, h2b, bnstats, gg[0], be_[0]);
    LAYER(1, 32, 64, false, true, h2b, h2a, bnstats + 0 * 256, gg[0], be_[0]);
    LAYER(2, 64, 128, false, true, h2a, h2b, bnstats + 1 * 256, gg[1], be_[1]);
    LAYER(3, 128, 64, false, true, h2b, h2a, bnstats + 2 * 256, gg[2], be_[2]);
#undef LAYER

    pool_head_k<<<G, 64, 0, stream>>>(h2a, gs, ge, bnstats + 3 * 256, gg[3], be_[3],
                                      invN, Wf, bfp, Wc, bc, (float*)d_out);
}

// Round 2
// 355.525 us; speedup vs baseline: 1.0956x; 1.0561x over previous
//
#include <hip/hip_runtime.h>
#include <math.h>

constexpr int BLK = 256;
constexpr int NBLKA = 256;     // phase-A blocks for edge bucketing

static inline int cdiv(long a, long b) { return (int)((a + b - 1) / b); }

typedef __attribute__((ext_vector_type(8))) short short8;
typedef __attribute__((ext_vector_type(4))) float floatx4;

// ---------------- bf16 helpers (RNE) -----------------------------------------
__device__ __forceinline__ unsigned short f2bf(float f) {
    unsigned u = __float_as_uint(f);
    unsigned r = u + 0x7fffu + ((u >> 16) & 1u);
    return (unsigned short)(r >> 16);
}
__device__ __forceinline__ float bf2f(unsigned short s) {
    return __uint_as_float(((unsigned)s) << 16);
}

// ============== CSR build via 2-phase bucket sort (NO global atomics) ========
// Bucket b covers nodes [b*256, b*256+256). histg layout: [z*nbkt + b].

__global__ void histA_k(const int* __restrict__ dst, int* __restrict__ histg,
                        int E, int nbkt, int chunk) {
    __shared__ int h[256];
    int tid = threadIdx.x, z = blockIdx.x;
    h[tid] = 0;
    __syncthreads();
    int e0 = z * chunk, e1 = min(E, e0 + chunk);
    for (int e = e0 + tid; e < e1; e += BLK) atomicAdd(&h[dst[e] >> 8], 1);
    __syncthreads();
    if (tid < nbkt) histg[z * nbkt + tid] = h[tid];
}

__global__ void bucket_scan_k(const int* __restrict__ histg, int* __restrict__ bucket_base,
                              int nbkt, int E, int* __restrict__ gs, int* __restrict__ ge,
                              int G, float* __restrict__ bnstats) {
    __shared__ int s[BLK];
    int t = threadIdx.x;
    int v = 0;
    if (t < nbkt)
        for (int z = 0; z < NBLKA; ++z) v += histg[z * nbkt + t];
    s[t] = v;
    __syncthreads();
    for (int o = 1; o < BLK; o <<= 1) {
        int tv = (t >= o) ? s[t - o] : 0;
        __syncthreads();
        s[t] += tv;
        __syncthreads();
    }
    if (t < nbkt) bucket_base[t] = s[t] - v;
    if (t == 0) bucket_base[nbkt] = E;
    for (int i = t; i < G; i += BLK) { gs[i] = 0x7fffffff; ge[i] = -1; }
    for (int i = t; i < 8192; i += BLK) bnstats[i] = 0.f;   // 4 layers x 8 shadows x 256
}

__global__ void blk_scan_k(int* __restrict__ histg, const int* __restrict__ bucket_base,
                           int nbkt) {
    __shared__ int s[BLK];
    int t = threadIdx.x, b = blockIdx.x;
    int v = histg[t * nbkt + b];
    s[t] = v;
    __syncthreads();
    for (int o = 1; o < BLK; o <<= 1) {
        int tv = (t >= o) ? s[t - o] : 0;
        __syncthreads();
        s[t] += tv;
        __syncthreads();
    }
    histg[t * nbkt + b] = bucket_base[b] + s[t] - v;
}

__global__ void scatterA_k(const int* __restrict__ src, const int* __restrict__ dst,
                           const int* __restrict__ histg, unsigned* __restrict__ ebkt,
                           int E, int nbkt, int chunk) {
    __shared__ int cur[256];
    int tid = threadIdx.x, z = blockIdx.x;
    if (tid < nbkt) cur[tid] = histg[z * nbkt + tid];
    __syncthreads();
    int e0 = z * chunk, e1 = min(E, e0 + chunk);
    for (int e = e0 + tid; e < e1; e += BLK) {
        int d = dst[e];
        int b = d >> 8;
        int pos = atomicAdd(&cur[b], 1);
        ebkt[pos] = ((unsigned)(d & 255) << 16) | (unsigned)src[e];
    }
}

// B: per-bucket CSR finalize (degrees->scan->self-loop->fill) + graph ranges.
__global__ void csrB_k(const unsigned* __restrict__ ebkt, const int* __restrict__ bucket_base,
                       int* __restrict__ off, unsigned short* __restrict__ csr,
                       const int* __restrict__ batch, int* __restrict__ gs,
                       int* __restrict__ ge, int N, int E, int nbkt) {
    __shared__ int dg[256];
    __shared__ int sc[256];
    int t = threadIdx.x, b = blockIdx.x;
    int n0 = b << 8;
    int cnt = min(256, N - n0);
    dg[t] = (t < cnt) ? 1 : 0;                     // self-loop
    __syncthreads();
    int e0 = bucket_base[b], e1 = bucket_base[b + 1];
    for (int e = e0 + t; e < e1; e += BLK) atomicAdd(&dg[ebkt[e] >> 16], 1);
    __syncthreads();
    int d = dg[t];
    sc[t] = d;
    __syncthreads();
    for (int o = 1; o < BLK; o <<= 1) {
        int tv = (t >= o) ? sc[t - o] : 0;
        __syncthreads();
        sc[t] += tv;
        __syncthreads();
    }
    int loff = sc[t] - d;                          // exclusive
    int csrbase = e0 + n0;                         // n0 self-loops precede bucket
    if (t < cnt) {
        off[n0 + t] = csrbase + loff;
        csr[csrbase + loff] = (unsigned short)(n0 + t);   // self-loop slot
        dg[t] = loff + 1;                          // cursor
    }
    if (b == nbkt - 1 && t == 0) off[N] = E + N;
    // graph ranges (batch sorted): boundary detection, this grid covers N.
    int n = n0 + t;
    if (n < N) {
        int bb = batch[n];
        if (n == 0) gs[bb] = 0;
        else {
            int pb = batch[n - 1];
            if (pb != bb) { gs[bb] = n; ge[pb] = n - 1; }
        }
        if (n == N - 1) ge[bb] = N - 1;
    }
    __syncthreads();
    for (int e = e0 + t; e < e1; e += BLK) {
        unsigned w = ebkt[e];
        int pos = atomicAdd(&dg[w >> 16], 1);
        csr[csrbase + pos] = (unsigned short)(w & 0xffff);
    }
}

// ---------------- self-contained MFMA GEMM (prep fused in prologue) -----------
// Single-y grid: A fragments are loaded ONCE per block and reused across all
// NOUT/16 column groups (previous version re-read A per blockIdx.y => up to 8x
// redundant A traffic). BN stats arrive as 8 shadow copies (summed here).
template <int K, int NOUT, bool AFP32, bool HASBN>
__launch_bounds__(256)
__global__ void gemm_fused(const void* __restrict__ av, const float* __restrict__ W,
                           const float* __restrict__ a_s, const float* __restrict__ a_d,
                           const float* __restrict__ bnst, const float* __restrict__ g_prev,
                           const float* __restrict__ be_prev, float invN,
                           unsigned short* __restrict__ hb,
                           float* __restrict__ asrc, float* __restrict__ adst, int N) {
    constexpr int KF = K / 32;
    constexpr int NY = NOUT / 16;
    __shared__ float s_sca[K], s_scc[K], s_rs[K], s_rd[K], s_bd[2];
    int tid = threadIdx.x;
    if (tid < K) {
        float a = 1.f, c = 0.f;
        if (HASBN) {
            float su = 0.f, sq = 0.f;
#pragma unroll
            for (int s = 0; s < 8; ++s) {
                su += bnst[s * 256 + tid];
                sq += bnst[s * 256 + 128 + tid];
            }
            float mu = su * invN;
            float var = sq * invN - mu * mu;
            a = g_prev[tid] * rsqrtf(var + 1e-5f);
            c = be_prev[tid] - mu * a;
        }
        s_sca[tid] = a; s_scc[tid] = c;
    }
    __syncthreads();
    {   // attention-dot vectors (every block: rows are block-partitioned now)
        if (tid < K) {
            const float* wr = W + (long)tid * NOUT;
            float rs = 0.f, rd = 0.f;
            for (int f = 0; f < NOUT; ++f) {
                float w = wr[f];
                rs += w * a_s[f];
                rd += w * a_d[f];
            }
            s_rs[tid] = rs; s_rd[tid] = rd;
        }
        __syncthreads();
        if (tid < 2) {
            const float* r = tid ? s_rd : s_rs;
            float b = 0.f;
            for (int k = 0; k < K; ++k) b += s_scc[k] * r[k];
            s_bd[tid] = b;
        }
        __syncthreads();
    }

    int wave = tid >> 6;
    int lane = tid & 63;
    int quad = lane >> 4;
    int r16 = lane & 15;
    int blockbase = blockIdx.x * 128;

    // ---- A fragments: load once, reuse for all column groups ----
    short8 afr[2][KF];
    bool valid[2];
#pragma unroll
    for (int rt = 0; rt < 2; ++rt) {
        int tilebase = blockbase + wave * 32 + rt * 16;
        valid[rt] = tilebase < N;
        if (!valid[rt]) continue;                       // wave-uniform
        int arow = min(tilebase + r16, N - 1);
        if (AFP32) {
            const float* xr = (const float*)av + (long)arow * K;
#pragma unroll
            for (int kk = 0; kk < KF; ++kk) {
                float4 x0 = *(const float4*)(xr + kk * 32 + quad * 8);
                float4 x1 = *(const float4*)(xr + kk * 32 + quad * 8 + 4);
                short8 a;
                a[0] = (short)f2bf(x0.x); a[1] = (short)f2bf(x0.y);
                a[2] = (short)f2bf(x0.z); a[3] = (short)f2bf(x0.w);
                a[4] = (short)f2bf(x1.x); a[5] = (short)f2bf(x1.y);
                a[6] = (short)f2bf(x1.z); a[7] = (short)f2bf(x1.w);
                afr[rt][kk] = a;
            }
        } else {
            const unsigned short* hr = (const unsigned short*)av + (long)arow * K;
#pragma unroll
            for (int kk = 0; kk < KF; ++kk)
                afr[rt][kk] = *(const short8*)(hr + kk * 32 + quad * 8);
        }
        // per-row attention dots (uses raw A scaled by BN coeffs)
        float ds = 0.f, dd = 0.f;
#pragma unroll
        for (int kk = 0; kk < KF; ++kk) {
            int kb = kk * 32 + quad * 8;
#pragma unroll
            for (int j = 0; j < 8; ++j) {
                int k = kb + j;
                float a = bf2f((unsigned short)afr[rt][kk][j]) * s_sca[k];
                ds += a * s_rs[k];
                dd += a * s_rd[k];
            }
        }
        ds += __shfl_xor(ds, 16, 64); ds += __shfl_xor(ds, 32, 64);
        dd += __shfl_xor(dd, 16, 64); dd += __shfl_xor(dd, 32, 64);
        int drow = tilebase + r16;
        if (quad == 0 && drow < N) {
            asrc[drow] = ds + s_bd[0];
            adst[drow] = dd + s_bd[1];
        }
    }

    // ---- column-group loop: build B fragment (BN-scaled), MFMA, store ----
#pragma unroll
    for (int y = 0; y < NY; ++y) {
        int col = y * 16 + r16;
        short8 bfr[KF];
        float biasp = 0.f;
#pragma unroll
        for (int kk = 0; kk < KF; ++kk) {
            short8 b;
#pragma unroll
            for (int j = 0; j < 8; ++j) {
                int k = kk * 32 + quad * 8 + j;
                float w = W[(long)k * NOUT + col];
                b[j] = (short)f2bf(s_sca[k] * w);
                biasp += s_scc[k] * w;
            }
            bfr[kk] = b;
        }
        biasp += __shfl_xor(biasp, 16, 64);
        biasp += __shfl_xor(biasp, 32, 64);

#pragma unroll
        for (int rt = 0; rt < 2; ++rt) {
            if (!valid[rt]) continue;                   // wave-uniform
            int tilebase = blockbase + wave * 32 + rt * 16;
            floatx4 acc = {0.f, 0.f, 0.f, 0.f};
#pragma unroll
            for (int kk = 0; kk < KF; ++kk)
                acc = __builtin_amdgcn_mfma_f32_16x16x32_bf16(afr[rt][kk], bfr[kk], acc, 0, 0, 0);
#pragma unroll
            for (int rr = 0; rr < 4; ++rr) {
                int srow = tilebase + quad * 4 + rr;
                if (srow < N) hb[(long)srow * NOUT + col] = f2bf(acc[rr] + biasp);
            }
        }
    }
}

// ---------------- fused softmax + gather + bias + leaky(0.01), bf16 out ------
// SINGLE-PASS online softmax: weights are exp(e) with no max-subtraction, so
// accumulate unnormalized acc += w*h[s] and sum += w together, scale by 1/sum
// at the end. TPN lanes per node compute w redundantly (cheap VALU) making
// csr/asrc loads same-address broadcasts; no shuffles, no two-pass.
template <int DOUT>
__global__ void gather_fused(const int* __restrict__ off,
                             const unsigned short* __restrict__ csr,
                             const float* __restrict__ asrc, const float* __restrict__ adst,
                             const unsigned short* __restrict__ hb,
                             const float* __restrict__ b,
                             unsigned short* __restrict__ out, int N) {
    constexpr int TPN = DOUT / 8;
    int t = blockIdx.x * blockDim.x + threadIdx.x;
    int d = t / TPN;
    if (d >= N) return;
    int l = t % TPN;
    int p0 = off[d], p1 = off[d + 1];
    float ad = adst[d];
    const int f0 = l * 8;

    float acc[8];
#pragma unroll
    for (int i = 0; i < 8; ++i) acc[i] = 0.f;
    float sum = 0.f;

#pragma unroll 2
    for (int p = p0; p < p1; ++p) {
        int s = csr[p];                           // broadcast across group
        float e = asrc[s] + ad;                   // broadcast load
        e = e > 0.f ? e : 0.2f * e;               // leaky_relu(0.2)
        float w = __expf(e);
        sum += w;
        const uint4 hv = *(const uint4*)(hb + (long)s * DOUT + f0);
        acc[0] += w * bf2f((unsigned short)(hv.x & 0xffff));
        acc[1] += w * bf2f((unsigned short)(hv.x >> 16));
        acc[2] += w * bf2f((unsigned short)(hv.y & 0xffff));
        acc[3] += w * bf2f((unsigned short)(hv.y >> 16));
        acc[4] += w * bf2f((unsigned short)(hv.z & 0xffff));
        acc[5] += w * bf2f((unsigned short)(hv.z >> 16));
        acc[6] += w * bf2f((unsigned short)(hv.w & 0xffff));
        acc[7] += w * bf2f((unsigned short)(hv.w >> 16));
    }
    float inv = 1.f / sum;                        // self-loop guarantees sum > 0

    float4 b0 = *(const float4*)(b + f0);
    float4 b1 = *(const float4*)(b + f0 + 4);
    float bb[8] = {b0.x, b0.y, b0.z, b0.w, b1.x, b1.y, b1.z, b1.w};
    ushort4 o0, o1;
#pragma unroll
    for (int i = 0; i < 8; ++i) {
        float v = acc[i] * inv + bb[i];
        v = v > 0.f ? v : 0.01f * v;             // leaky_relu(0.01)
        unsigned short hv = f2bf(v);
        if (i < 4) ((unsigned short*)&o0)[i] = hv;
        else       ((unsigned short*)&o1)[i - 4] = hv;
    }
    *(ushort4*)(out + (long)d * DOUT + f0) = o0;
    *(ushort4*)(out + (long)d * DOUT + f0 + 4) = o1;
}

// ---------------- BN statistics over bf16 activations ------------------------
// 240 blocks (vs 120: engage >120 CUs); global flush into 8 shadow copies
// (bn + (blk&7)*256) to cut per-address atomic serialization 4x. Consumers
// (gemm prologue, pool head) sum the 8 shadows.
template <int DOUT>
__global__ void stats_k(const unsigned short* __restrict__ y, float* __restrict__ bn, int N) {
    constexpr int QPR = DOUT / 8;
    __shared__ float ssum[DOUT];
    __shared__ float ssq[DOUT];
    for (int i = threadIdx.x; i < DOUT; i += blockDim.x) { ssum[i] = 0.f; ssq[i] = 0.f; }
    __syncthreads();
    long total = (long)N * QPR;
    long stride = (long)gridDim.x * blockDim.x;     // multiple of QPR
    long t0 = (long)blockIdx.x * blockDim.x + threadIdx.x;
    int f0 = (int)(t0 % QPR) * 8;
    float ls[8], lq[8];
#pragma unroll
    for (int i = 0; i < 8; ++i) { ls[i] = 0.f; lq[i] = 0.f; }
    for (long t = t0; t < total; t += stride) {
        uint4 hv = *(const uint4*)(y + t * 8);
        unsigned vv[4] = {hv.x, hv.y, hv.z, hv.w};
#pragma unroll
        for (int q = 0; q < 4; ++q) {
            float v0 = bf2f((unsigned short)(vv[q] & 0xffff));
            float v1 = bf2f((unsigned short)(vv[q] >> 16));
            ls[2 * q] += v0;     lq[2 * q] += v0 * v0;
            ls[2 * q + 1] += v1; lq[2 * q + 1] += v1 * v1;
        }
    }
#pragma unroll
    for (int i = 0; i < 8; ++i) {
        atomicAdd(&ssum[f0 + i], ls[i]);
        atomicAdd(&ssq[f0 + i], lq[i]);
    }
    __syncthreads();
    float* base = bn + (blockIdx.x & 7) * 256;
    for (int i = threadIdx.x; i < DOUT; i += blockDim.x) {
        atomicAdd(&base[i], ssum[i]);
        atomicAdd(&base[128 + i], ssq[i]);
    }
}

// ---------------- pool (with inline final BN) + MLP head, fused --------------
// 256 threads: 4 row-partials per feature (LDS combine) -> ~4x the row-scan
// parallelism of the old 64-thread version.
__global__ void pool_head_k(const unsigned short* __restrict__ h, const int* __restrict__ gs,
                            const int* __restrict__ ge, const float* __restrict__ bnst,
                            const float* __restrict__ g4, const float* __restrict__ be4,
                            float invN, const float* __restrict__ Wf,
                            const float* __restrict__ bf, const float* __restrict__ Wc,
                            const float* __restrict__ bc, float* __restrict__ out) {
    int g = blockIdx.x;
    int t = threadIdx.x;                          // 256 threads
    int f = t & 63, sub = t >> 6;                 // 4 row-subsets
    __shared__ float pp[4][64];
    __shared__ float p[64];
    __shared__ float z[32];
    int s0 = gs[g], s1 = ge[g];
    float acc = 0.f;
    if (s0 <= s1)
        for (int n = s0 + sub; n <= s1; n += 4) acc += bf2f(h[(long)n * 64 + f]);
    pp[sub][f] = acc;
    __syncthreads();
    if (t < 64) {
        float su = 0.f, sq = 0.f;
#pragma unroll
        for (int s = 0; s < 8; ++s) {
            su += bnst[s * 256 + t];
            sq += bnst[s * 256 + 128 + t];
        }
        float mu = su * invN;
        float var = sq * invN - mu * mu;
        float a = g4[t] * rsqrtf(var + 1e-5f);
        float c = be4[t] - mu * a;
        float cnt = (s0 <= s1) ? (float)(s1 - s0 + 1) : 0.f;
        p[t] = a * (pp[0][t] + pp[1][t] + pp[2][t] + pp[3][t]) + cnt * c;
    }
    __syncthreads();
    if (t < 32) {
        float zacc = bf[t];
#pragma unroll
        for (int ff = 0; ff < 64; ++ff) zacc += p[ff] * Wf[ff * 32 + t];
        z[t] = zacc > 0.f ? zacc : 0.01f * zacc;
    }
    __syncthreads();
    if (t < 8) {
        float oacc = bc[t];
#pragma unroll
        for (int o = 0; o < 32; ++o) oacc += z[o] * Wc[o * 8 + t];
        out[(long)g * 8 + t] = 1.f / (1.f + __expf(-oacc));
    }
}

extern "C" void kernel_launch(void* const* d_in, const int* in_sizes, int n_in,
                              void* d_out, int out_size, void* d_ws, size_t ws_size,
                              hipStream_t stream) {
    const float* x   = (const float*)d_in[0];
    const int* ei    = (const int*)d_in[1];
    const int* batch = (const int*)d_in[2];
    const int N  = in_sizes[2];
    const int E  = in_sizes[1] / 2;
    const int ET = E + N;
    const int G  = out_size / 8;
    const int* src = ei;
    const int* dst = ei + E;

    const float *W[4], *as_[4], *ad_[4], *bb[4], *gg[4], *be_[4];
    for (int i = 0; i < 4; ++i) {
        W[i]   = (const float*)d_in[3 + 6 * i];
        as_[i] = (const float*)d_in[4 + 6 * i];
        ad_[i] = (const float*)d_in[5 + 6 * i];
        bb[i]  = (const float*)d_in[6 + 6 * i];
        gg[i]  = (const float*)d_in[7 + 6 * i];
        be_[i] = (const float*)d_in[8 + 6 * i];
    }
    const float* Wf = (const float*)d_in[27];
    const float* bfp = (const float*)d_in[28];
    const float* Wc = (const float*)d_in[29];
    const float* bc = (const float*)d_in[30];

    float* ws = (float*)d_ws;
    long off_ = 0;
    auto alloc = [&](long nelem) { float* p = ws + off_; off_ += (nelem + 3) & ~3L; return p; };
    unsigned short* h2a = (unsigned short*)alloc((long)N * 64);  // N x 128 bf16
    unsigned short* h2b = (unsigned short*)alloc((long)N * 64);
    unsigned short* hb  = (unsigned short*)alloc((long)N * 64);
    float* asrc     = alloc(N);
    float* adst     = alloc(N);
    float* bnstats  = alloc(4 * 2048);      // per-layer: 8 shadows x (sum[128]|sq[128])
    unsigned* ebkt  = (unsigned*)alloc(E);
    int* histg      = (int*)alloc((long)NBLKA * 256);
    int* bucket_base = (int*)alloc(260);
    int* off        = (int*)alloc(N + 1);
    unsigned short* csr = (unsigned short*)alloc(ET / 2 + 2);
    int* gs         = (int*)alloc(G);
    int* ge         = (int*)alloc(G);
    (void)ws_size; (void)n_in;

    const int nbkt = cdiv(N, 256);          // 196
    const int chunk = cdiv(E, NBLKA);
    const float invN = 1.f / (float)N;

    // ---- CSR build (bucket sort, no global atomics) + graph ranges ----
    histA_k<<<NBLKA, BLK, 0, stream>>>(dst, histg, E, nbkt, chunk);
    bucket_scan_k<<<1, BLK, 0, stream>>>(histg, bucket_base, nbkt, E, gs, ge, G, bnstats);
    blk_scan_k<<<nbkt, BLK, 0, stream>>>(histg, bucket_base, nbkt);
    scatterA_k<<<NBLKA, BLK, 0, stream>>>(src, dst, histg, ebkt, E, nbkt, chunk);
    csrB_k<<<nbkt, BLK, 0, stream>>>(ebkt, bucket_base, off, csr, batch, gs, ge, N, E, nbkt);

#define LAYER(i, DIN, DOUT, AFP32, HASBN, INP, OUTP, BNPREV, GPREV, BEPREV)               \
    do {                                                                                  \
        gemm_fused<DIN, DOUT, AFP32, HASBN>                                               \
            <<<cdiv(N, 128), 256, 0, stream>>>(                                           \
                INP, W[i], as_[i], ad_[i], BNPREV, GPREV, BEPREV, invN,                   \
                hb, asrc, adst, N);                                                       \
        gather_fused<DOUT><<<cdiv((long)N * (DOUT / 8), BLK), BLK, 0, stream>>>(          \
            off, csr, asrc, adst, hb, bb[i], OUTP, N);                                    \
        stats_k<DOUT><<<240, BLK, 0, stream>>>(OUTP, bnstats + i * 2048, N);              \
    } while (0)

    LAYER(0, 128, 32, true, false, x, h2b, bnstats, gg[0], be_[0]);
    LAYER(1, 32, 64, false, true, h2b, h2a, bnstats + 0 * 2048, gg[0], be_[0]);
    LAYER(2, 64, 128, false, true, h2a, h2b, bnstats + 1 * 2048, gg[1], be_[1]);
    LAYER(3, 128, 64, false, true, h2b, h2a, bnstats + 2 * 2048, gg[2], be_[2]);
#undef LAYER

    pool_head_k<<<G, 256, 0, stream>>>(h2a, gs, ge, bnstats + 3 * 2048, gg[3], be_[3],
                                       invN, Wf, bfp, Wc, bc, (float*)d_out);
}

// Round 3
// 353.248 us; speedup vs baseline: 1.1026x; 1.0064x over previous
//
#include <hip/hip_runtime.h>
#include <math.h>

constexpr int BLK = 256;
constexpr int NBLKA = 256;     // phase-A blocks for edge bucketing

static inline int cdiv(long a, long b) { return (int)((a + b - 1) / b); }

typedef __attribute__((ext_vector_type(8))) short short8;
typedef __attribute__((ext_vector_type(4))) float floatx4;

// ---------------- bf16 helpers (RNE) -----------------------------------------
__device__ __forceinline__ unsigned short f2bf(float f) {
    unsigned u = __float_as_uint(f);
    unsigned r = u + 0x7fffu + ((u >> 16) & 1u);
    return (unsigned short)(r >> 16);
}
__device__ __forceinline__ float bf2f(unsigned short s) {
    return __uint_as_float(((unsigned)s) << 16);
}

// ============== CSR build via 2-phase bucket sort (NO global atomics) ========
// Bucket b covers nodes [b*256, b*256+256). histg layout: [z*nbkt + b].

__global__ void histA_k(const int* __restrict__ dst, int* __restrict__ histg,
                        int E, int nbkt, int chunk) {
    __shared__ int h[256];
    int tid = threadIdx.x, z = blockIdx.x;
    h[tid] = 0;
    __syncthreads();
    int e0 = z * chunk, e1 = min(E, e0 + chunk);
    for (int e = e0 + tid; e < e1; e += BLK) atomicAdd(&h[dst[e] >> 8], 1);
    __syncthreads();
    if (tid < nbkt) histg[z * nbkt + tid] = h[tid];
}

// Per-bucket exclusive scan over the 256 z-chunks (196 parallel blocks) and
// per-bucket totals. Replaces the old single-block 200KB serial column-sum.
__global__ void blk_scan2_k(int* __restrict__ histg, int* __restrict__ bsum, int nbkt) {
    __shared__ int s[BLK];
    int t = threadIdx.x, b = blockIdx.x;
    int v = histg[t * nbkt + b];
    s[t] = v;
    __syncthreads();
    for (int o = 1; o < BLK; o <<= 1) {
        int tv = (t >= o) ? s[t - o] : 0;
        __syncthreads();
        s[t] += tv;
        __syncthreads();
    }
    histg[t * nbkt + b] = s[t] - v;            // exclusive, no base yet
    if (t == BLK - 1) bsum[b] = s[t];          // bucket total
}

// Tiny single block: scan 196 bucket totals (LDS-only) + sentinel/stat inits.
__global__ void scan_base_k(const int* __restrict__ bsum, int* __restrict__ bucket_base,
                            int nbkt, int E, int* __restrict__ gs, int* __restrict__ ge,
                            int G, float* __restrict__ bnstats) {
    __shared__ int s[BLK];
    int t = threadIdx.x;
    int v = (t < nbkt) ? bsum[t] : 0;
    s[t] = v;
    __syncthreads();
    for (int o = 1; o < BLK; o <<= 1) {
        int tv = (t >= o) ? s[t - o] : 0;
        __syncthreads();
        s[t] += tv;
        __syncthreads();
    }
    if (t < nbkt) bucket_base[t] = s[t] - v;
    if (t == 0) bucket_base[nbkt] = E;
    for (int i = t; i < G; i += BLK) { gs[i] = 0x7fffffff; ge[i] = -1; }
    for (int i = t; i < 8192; i += BLK) bnstats[i] = 0.f;   // 4 layers x 8 shadows x 256
}

__global__ void scatterA_k(const int* __restrict__ src, const int* __restrict__ dst,
                           const int* __restrict__ histg, const int* __restrict__ bucket_base,
                           unsigned* __restrict__ ebkt, int E, int nbkt, int chunk) {
    __shared__ int cur[256];
    int tid = threadIdx.x, z = blockIdx.x;
    if (tid < nbkt) cur[tid] = histg[z * nbkt + tid] + bucket_base[tid];
    __syncthreads();
    int e0 = z * chunk, e1 = min(E, e0 + chunk);
    for (int e = e0 + tid; e < e1; e += BLK) {
        int d = dst[e];
        int b = d >> 8;
        int pos = atomicAdd(&cur[b], 1);
        ebkt[pos] = ((unsigned)(d & 255) << 16) | (unsigned)src[e];
    }
}

// B: per-bucket CSR finalize (degrees->scan->self-loop->fill) + graph ranges.
__global__ void csrB_k(const unsigned* __restrict__ ebkt, const int* __restrict__ bucket_base,
                       int* __restrict__ off, unsigned short* __restrict__ csr,
                       const int* __restrict__ batch, int* __restrict__ gs,
                       int* __restrict__ ge, int N, int E, int nbkt) {
    __shared__ int dg[256];
    __shared__ int sc[256];
    int t = threadIdx.x, b = blockIdx.x;
    int n0 = b << 8;
    int cnt = min(256, N - n0);
    dg[t] = (t < cnt) ? 1 : 0;                     // self-loop
    __syncthreads();
    int e0 = bucket_base[b], e1 = bucket_base[b + 1];
    for (int e = e0 + t; e < e1; e += BLK) atomicAdd(&dg[ebkt[e] >> 16], 1);
    __syncthreads();
    int d = dg[t];
    sc[t] = d;
    __syncthreads();
    for (int o = 1; o < BLK; o <<= 1) {
        int tv = (t >= o) ? sc[t - o] : 0;
        __syncthreads();
        sc[t] += tv;
        __syncthreads();
    }
    int loff = sc[t] - d;                          // exclusive
    int csrbase = e0 + n0;                         // n0 self-loops precede bucket
    if (t < cnt) {
        off[n0 + t] = csrbase + loff;
        csr[csrbase + loff] = (unsigned short)(n0 + t);   // self-loop slot
        dg[t] = loff + 1;                          // cursor
    }
    if (b == nbkt - 1 && t == 0) off[N] = E + N;
    // graph ranges (batch sorted): boundary detection, this grid covers N.
    int n = n0 + t;
    if (n < N) {
        int bb = batch[n];
        if (n == 0) gs[bb] = 0;
        else {
            int pb = batch[n - 1];
            if (pb != bb) { gs[bb] = n; ge[pb] = n - 1; }
        }
        if (n == N - 1) ge[bb] = N - 1;
    }
    __syncthreads();
    for (int e = e0 + t; e < e1; e += BLK) {
        unsigned w = ebkt[e];
        int pos = atomicAdd(&dg[w >> 16], 1);
        csr[csrbase + pos] = (unsigned short)(w & 0xffff);
    }
}

// ---------------- self-contained MFMA GEMM (prep fused in prologue) -----------
// Single-y grid: A fragments loaded ONCE per block, reused across all NOUT/16
// column groups. BN stats arrive as 8 shadow copies (summed here).
template <int K, int NOUT, bool AFP32, bool HASBN>
__launch_bounds__(256)
__global__ void gemm_fused(const void* __restrict__ av, const float* __restrict__ W,
                           const float* __restrict__ a_s, const float* __restrict__ a_d,
                           const float* __restrict__ bnst, const float* __restrict__ g_prev,
                           const float* __restrict__ be_prev, float invN,
                           unsigned short* __restrict__ hb,
                           float* __restrict__ asrc, float* __restrict__ adst, int N) {
    constexpr int KF = K / 32;
    constexpr int NY = NOUT / 16;
    __shared__ float s_sca[K], s_scc[K], s_rs[K], s_rd[K], s_bd[2];
    int tid = threadIdx.x;
    if (tid < K) {
        float a = 1.f, c = 0.f;
        if (HASBN) {
            float su = 0.f, sq = 0.f;
#pragma unroll
            for (int s = 0; s < 8; ++s) {
                su += bnst[s * 256 + tid];
                sq += bnst[s * 256 + 128 + tid];
            }
            float mu = su * invN;
            float var = sq * invN - mu * mu;
            a = g_prev[tid] * rsqrtf(var + 1e-5f);
            c = be_prev[tid] - mu * a;
        }
        s_sca[tid] = a; s_scc[tid] = c;
    }
    __syncthreads();
    {   // attention-dot vectors
        if (tid < K) {
            const float* wr = W + (long)tid * NOUT;
            float rs = 0.f, rd = 0.f;
            for (int f = 0; f < NOUT; ++f) {
                float w = wr[f];
                rs += w * a_s[f];
                rd += w * a_d[f];
            }
            s_rs[tid] = rs; s_rd[tid] = rd;
        }
        __syncthreads();
        if (tid < 2) {
            const float* r = tid ? s_rd : s_rs;
            float b = 0.f;
            for (int k = 0; k < K; ++k) b += s_scc[k] * r[k];
            s_bd[tid] = b;
        }
        __syncthreads();
    }

    int wave = tid >> 6;
    int lane = tid & 63;
    int quad = lane >> 4;
    int r16 = lane & 15;
    int blockbase = blockIdx.x * 128;

    // ---- A fragments: load once, reuse for all column groups ----
    short8 afr[2][KF];
    bool valid[2];
#pragma unroll
    for (int rt = 0; rt < 2; ++rt) {
        int tilebase = blockbase + wave * 32 + rt * 16;
        valid[rt] = tilebase < N;
        if (!valid[rt]) continue;                       // wave-uniform
        int arow = min(tilebase + r16, N - 1);
        if (AFP32) {
            const float* xr = (const float*)av + (long)arow * K;
#pragma unroll
            for (int kk = 0; kk < KF; ++kk) {
                float4 x0 = *(const float4*)(xr + kk * 32 + quad * 8);
                float4 x1 = *(const float4*)(xr + kk * 32 + quad * 8 + 4);
                short8 a;
                a[0] = (short)f2bf(x0.x); a[1] = (short)f2bf(x0.y);
                a[2] = (short)f2bf(x0.z); a[3] = (short)f2bf(x0.w);
                a[4] = (short)f2bf(x1.x); a[5] = (short)f2bf(x1.y);
                a[6] = (short)f2bf(x1.z); a[7] = (short)f2bf(x1.w);
                afr[rt][kk] = a;
            }
        } else {
            const unsigned short* hr = (const unsigned short*)av + (long)arow * K;
#pragma unroll
            for (int kk = 0; kk < KF; ++kk)
                afr[rt][kk] = *(const short8*)(hr + kk * 32 + quad * 8);
        }
        // per-row attention dots (raw A scaled by BN coeffs)
        float ds = 0.f, dd = 0.f;
#pragma unroll
        for (int kk = 0; kk < KF; ++kk) {
            int kb = kk * 32 + quad * 8;
#pragma unroll
            for (int j = 0; j < 8; ++j) {
                int k = kb + j;
                float a = bf2f((unsigned short)afr[rt][kk][j]) * s_sca[k];
                ds += a * s_rs[k];
                dd += a * s_rd[k];
            }
        }
        ds += __shfl_xor(ds, 16, 64); ds += __shfl_xor(ds, 32, 64);
        dd += __shfl_xor(dd, 16, 64); dd += __shfl_xor(dd, 32, 64);
        int drow = tilebase + r16;
        if (quad == 0 && drow < N) {
            asrc[drow] = ds + s_bd[0];
            adst[drow] = dd + s_bd[1];
        }
    }

    // ---- column-group loop: build B fragment (BN-scaled), MFMA, store ----
#pragma unroll
    for (int y = 0; y < NY; ++y) {
        int col = y * 16 + r16;
        short8 bfr[KF];
        float biasp = 0.f;
#pragma unroll
        for (int kk = 0; kk < KF; ++kk) {
            short8 b;
#pragma unroll
            for (int j = 0; j < 8; ++j) {
                int k = kk * 32 + quad * 8 + j;
                float w = W[(long)k * NOUT + col];
                b[j] = (short)f2bf(s_sca[k] * w);
                biasp += s_scc[k] * w;
            }
            bfr[kk] = b;
        }
        biasp += __shfl_xor(biasp, 16, 64);
        biasp += __shfl_xor(biasp, 32, 64);

#pragma unroll
        for (int rt = 0; rt < 2; ++rt) {
            if (!valid[rt]) continue;                   // wave-uniform
            int tilebase = blockbase + wave * 32 + rt * 16;
            floatx4 acc = {0.f, 0.f, 0.f, 0.f};
#pragma unroll
            for (int kk = 0; kk < KF; ++kk)
                acc = __builtin_amdgcn_mfma_f32_16x16x32_bf16(afr[rt][kk], bfr[kk], acc, 0, 0, 0);
#pragma unroll
            for (int rr = 0; rr < 4; ++rr) {
                int srow = tilebase + quad * 4 + rr;
                if (srow < N) hb[(long)srow * NOUT + col] = f2bf(acc[rr] + biasp);
            }
        }
    }
}

// ---------------- fused softmax + gather + bias + leaky(0.01), bf16 out ------
// Single-pass online softmax (exp without max-subtraction; |e| is O(1)).
// FPL = features per lane (8 or 16). FPL=16 halves the per-edge redundant
// weight computation and broadcast loads for the wide layers at unchanged
// byte traffic.
template <int DOUT, int FPL>
__global__ void gather_fused(const int* __restrict__ off,
                             const unsigned short* __restrict__ csr,
                             const float* __restrict__ asrc, const float* __restrict__ adst,
                             const unsigned short* __restrict__ hb,
                             const float* __restrict__ b,
                             unsigned short* __restrict__ out, int N) {
    constexpr int TPN = DOUT / FPL;
    constexpr int NV = FPL / 8;
    int t = blockIdx.x * blockDim.x + threadIdx.x;
    int d = t / TPN;
    if (d >= N) return;
    int l = t % TPN;
    int p0 = off[d], p1 = off[d + 1];
    float ad = adst[d];
    const int f0 = l * FPL;

    float acc[FPL];
#pragma unroll
    for (int i = 0; i < FPL; ++i) acc[i] = 0.f;
    float sum = 0.f;

#pragma unroll 2
    for (int p = p0; p < p1; ++p) {
        int s = csr[p];                           // broadcast across group
        float e = asrc[s] + ad;                   // broadcast load
        e = e > 0.f ? e : 0.2f * e;               // leaky_relu(0.2)
        float w = __expf(e);
        sum += w;
        const unsigned short* hr = hb + (long)s * DOUT + f0;
#pragma unroll
        for (int v = 0; v < NV; ++v) {
            const uint4 hv = *(const uint4*)(hr + v * 8);
            acc[v * 8 + 0] += w * bf2f((unsigned short)(hv.x & 0xffff));
            acc[v * 8 + 1] += w * bf2f((unsigned short)(hv.x >> 16));
            acc[v * 8 + 2] += w * bf2f((unsigned short)(hv.y & 0xffff));
            acc[v * 8 + 3] += w * bf2f((unsigned short)(hv.y >> 16));
            acc[v * 8 + 4] += w * bf2f((unsigned short)(hv.z & 0xffff));
            acc[v * 8 + 5] += w * bf2f((unsigned short)(hv.z >> 16));
            acc[v * 8 + 6] += w * bf2f((unsigned short)(hv.w & 0xffff));
            acc[v * 8 + 7] += w * bf2f((unsigned short)(hv.w >> 16));
        }
    }
    float inv = 1.f / sum;                        // self-loop guarantees sum > 0

#pragma unroll
    for (int v = 0; v < NV; ++v) {
        float4 b0 = *(const float4*)(b + f0 + v * 8);
        float4 b1 = *(const float4*)(b + f0 + v * 8 + 4);
        float bbv[8] = {b0.x, b0.y, b0.z, b0.w, b1.x, b1.y, b1.z, b1.w};
        unsigned pk[4];
#pragma unroll
        for (int i = 0; i < 4; ++i) {
            float v0 = acc[v * 8 + 2 * i] * inv + bbv[2 * i];
            float v1 = acc[v * 8 + 2 * i + 1] * inv + bbv[2 * i + 1];
            v0 = v0 > 0.f ? v0 : 0.01f * v0;      // leaky_relu(0.01)
            v1 = v1 > 0.f ? v1 : 0.01f * v1;
            pk[i] = (unsigned)f2bf(v0) | ((unsigned)f2bf(v1) << 16);
        }
        *(uint4*)(out + (long)d * DOUT + f0 + v * 8) = uint4{pk[0], pk[1], pk[2], pk[3]};
    }
}

// ---------------- BN statistics over bf16 activations ------------------------
// 240 blocks; global flush into 8 shadow copies (bn + (blk&7)*256) to cut
// per-address atomic serialization. Consumers sum the 8 shadows.
template <int DOUT>
__global__ void stats_k(const unsigned short* __restrict__ y, float* __restrict__ bn, int N) {
    constexpr int QPR = DOUT / 8;
    __shared__ float ssum[DOUT];
    __shared__ float ssq[DOUT];
    for (int i = threadIdx.x; i < DOUT; i += blockDim.x) { ssum[i] = 0.f; ssq[i] = 0.f; }
    __syncthreads();
    long total = (long)N * QPR;
    long stride = (long)gridDim.x * blockDim.x;     // multiple of QPR
    long t0 = (long)blockIdx.x * blockDim.x + threadIdx.x;
    int f0 = (int)(t0 % QPR) * 8;
    float ls[8], lq[8];
#pragma unroll
    for (int i = 0; i < 8; ++i) { ls[i] = 0.f; lq[i] = 0.f; }
    for (long t = t0; t < total; t += stride) {
        uint4 hv = *(const uint4*)(y + t * 8);
        unsigned vv[4] = {hv.x, hv.y, hv.z, hv.w};
#pragma unroll
        for (int q = 0; q < 4; ++q) {
            float v0 = bf2f((unsigned short)(vv[q] & 0xffff));
            float v1 = bf2f((unsigned short)(vv[q] >> 16));
            ls[2 * q] += v0;     lq[2 * q] += v0 * v0;
            ls[2 * q + 1] += v1; lq[2 * q + 1] += v1 * v1;
        }
    }
#pragma unroll
    for (int i = 0; i < 8; ++i) {
        atomicAdd(&ssum[f0 + i], ls[i]);
        atomicAdd(&ssq[f0 + i], lq[i]);
    }
    __syncthreads();
    float* base = bn + (blockIdx.x & 7) * 256;
    for (int i = threadIdx.x; i < DOUT; i += blockDim.x) {
        atomicAdd(&base[i], ssum[i]);
        atomicAdd(&base[128 + i], ssq[i]);
    }
}

// ---------------- pool (with inline final BN) + MLP head, fused --------------
__global__ void pool_head_k(const unsigned short* __restrict__ h, const int* __restrict__ gs,
                            const int* __restrict__ ge, const float* __restrict__ bnst,
                            const float* __restrict__ g4, const float* __restrict__ be4,
                            float invN, const float* __restrict__ Wf,
                            const float* __restrict__ bf, const float* __restrict__ Wc,
                            const float* __restrict__ bc, float* __restrict__ out) {
    int g = blockIdx.x;
    int t = threadIdx.x;                          // 256 threads
    int f = t & 63, sub = t >> 6;                 // 4 row-subsets
    __shared__ float pp[4][64];
    __shared__ float p[64];
    __shared__ float z[32];
    int s0 = gs[g], s1 = ge[g];
    float acc = 0.f;
    if (s0 <= s1)
        for (int n = s0 + sub; n <= s1; n += 4) acc += bf2f(h[(long)n * 64 + f]);
    pp[sub][f] = acc;
    __syncthreads();
    if (t < 64) {
        float su = 0.f, sq = 0.f;
#pragma unroll
        for (int s = 0; s < 8; ++s) {
            su += bnst[s * 256 + t];
            sq += bnst[s * 256 + 128 + t];
        }
        float mu = su * invN;
        float var = sq * invN - mu * mu;
        float a = g4[t] * rsqrtf(var + 1e-5f);
        float c = be4[t] - mu * a;
        float cnt = (s0 <= s1) ? (float)(s1 - s0 + 1) : 0.f;
        p[t] = a * (pp[0][t] + pp[1][t] + pp[2][t] + pp[3][t]) + cnt * c;
    }
    __syncthreads();
    if (t < 32) {
        float zacc = bf[t];
#pragma unroll
        for (int ff = 0; ff < 64; ++ff) zacc += p[ff] * Wf[ff * 32 + t];
        z[t] = zacc > 0.f ? zacc : 0.01f * zacc;
    }
    __syncthreads();
    if (t < 8) {
        float oacc = bc[t];
#pragma unroll
        for (int o = 0; o < 32; ++o) oacc += z[o] * Wc[o * 8 + t];
        out[(long)g * 8 + t] = 1.f / (1.f + __expf(-oacc));
    }
}

extern "C" void kernel_launch(void* const* d_in, const int* in_sizes, int n_in,
                              void* d_out, int out_size, void* d_ws, size_t ws_size,
                              hipStream_t stream) {
    const float* x   = (const float*)d_in[0];
    const int* ei    = (const int*)d_in[1];
    const int* batch = (const int*)d_in[2];
    const int N  = in_sizes[2];
    const int E  = in_sizes[1] / 2;
    const int ET = E + N;
    const int G  = out_size / 8;
    const int* src = ei;
    const int* dst = ei + E;

    const float *W[4], *as_[4], *ad_[4], *bb[4], *gg[4], *be_[4];
    for (int i = 0; i < 4; ++i) {
        W[i]   = (const float*)d_in[3 + 6 * i];
        as_[i] = (const float*)d_in[4 + 6 * i];
        ad_[i] = (const float*)d_in[5 + 6 * i];
        bb[i]  = (const float*)d_in[6 + 6 * i];
        gg[i]  = (const float*)d_in[7 + 6 * i];
        be_[i] = (const float*)d_in[8 + 6 * i];
    }
    const float* Wf = (const float*)d_in[27];
    const float* bfp = (const float*)d_in[28];
    const float* Wc = (const float*)d_in[29];
    const float* bc = (const float*)d_in[30];

    float* ws = (float*)d_ws;
    long off_ = 0;
    auto alloc = [&](long nelem) { float* p = ws + off_; off_ += (nelem + 3) & ~3L; return p; };
    unsigned short* h2a = (unsigned short*)alloc((long)N * 64);  // N x 128 bf16
    unsigned short* h2b = (unsigned short*)alloc((long)N * 64);
    unsigned short* hb  = (unsigned short*)alloc((long)N * 64);
    float* asrc     = alloc(N);
    float* adst     = alloc(N);
    float* bnstats  = alloc(4 * 2048);      // per-layer: 8 shadows x (sum[128]|sq[128])
    unsigned* ebkt  = (unsigned*)alloc(E);
    int* histg      = (int*)alloc((long)NBLKA * 256);
    int* bucket_base = (int*)alloc(260);
    int* bsum       = (int*)alloc(256);
    int* off        = (int*)alloc(N + 1);
    unsigned short* csr = (unsigned short*)alloc(ET / 2 + 2);
    int* gs         = (int*)alloc(G);
    int* ge         = (int*)alloc(G);
    (void)ws_size; (void)n_in;

    const int nbkt = cdiv(N, 256);          // 196
    const int chunk = cdiv(E, NBLKA);
    const float invN = 1.f / (float)N;

    // ---- CSR build (bucket sort, no global atomics) + graph ranges ----
    histA_k<<<NBLKA, BLK, 0, stream>>>(dst, histg, E, nbkt, chunk);
    blk_scan2_k<<<nbkt, BLK, 0, stream>>>(histg, bsum, nbkt);
    scan_base_k<<<1, BLK, 0, stream>>>(bsum, bucket_base, nbkt, E, gs, ge, G, bnstats);
    scatterA_k<<<NBLKA, BLK, 0, stream>>>(src, dst, histg, bucket_base, ebkt, E, nbkt, chunk);
    csrB_k<<<nbkt, BLK, 0, stream>>>(ebkt, bucket_base, off, csr, batch, gs, ge, N, E, nbkt);

#define LAYER(i, DIN, DOUT, FPL, AFP32, HASBN, INP, OUTP, BNPREV, GPREV, BEPREV)          \
    do {                                                                                  \
        gemm_fused<DIN, DOUT, AFP32, HASBN>                                               \
            <<<cdiv(N, 128), 256, 0, stream>>>(                                           \
                INP, W[i], as_[i], ad_[i], BNPREV, GPREV, BEPREV, invN,                   \
                hb, asrc, adst, N);                                                       \
        gather_fused<DOUT, FPL><<<cdiv((long)N * (DOUT / FPL), BLK), BLK, 0, stream>>>(   \
            off, csr, asrc, adst, hb, bb[i], OUTP, N);                                    \
        stats_k<DOUT><<<240, BLK, 0, stream>>>(OUTP, bnstats + i * 2048, N);              \
    } while (0)

    LAYER(0, 128, 32, 8,  true,  false, x,   h2b, bnstats,            gg[0], be_[0]);
    LAYER(1, 32,  64, 16, false, true,  h2b, h2a, bnstats + 0 * 2048, gg[0], be_[0]);
    LAYER(2, 64, 128, 16, false, true,  h2a, h2b, bnstats + 1 * 2048, gg[1], be_[1]);
    LAYER(3, 128, 64, 16, false, true,  h2b, h2a, bnstats + 2 * 2048, gg[2], be_[2]);
#undef LAYER

    pool_head_k<<<G, 256, 0, stream>>>(h2a, gs, ge, bnstats + 3 * 2048, gg[3], be_[3],
                                       invN, Wf, bfp, Wc, bc, (float*)d_out);
}

// Round 4
// 344.621 us; speedup vs baseline: 1.1302x; 1.0250x over previous
//
#include <hip/hip_runtime.h>
#include <math.h>

constexpr int BLK = 256;
constexpr int NBLKA = 256;     // phase-A blocks for edge bucketing
constexpr int NSH = 16;        // BN-stat shadow copies (atomic spread)

static inline int cdiv(long a, long b) { return (int)((a + b - 1) / b); }

typedef __attribute__((ext_vector_type(8))) short short8;
typedef __attribute__((ext_vector_type(4))) float floatx4;

// ---------------- bf16 helpers (RNE) -----------------------------------------
__device__ __forceinline__ unsigned short f2bf(float f) {
    unsigned u = __float_as_uint(f);
    unsigned r = u + 0x7fffu + ((u >> 16) & 1u);
    return (unsigned short)(r >> 16);
}
__device__ __forceinline__ float bf2f(unsigned short s) {
    return __uint_as_float(((unsigned)s) << 16);
}

// ============== CSR build via 2-phase bucket sort (NO global atomics) ========
// Bucket b covers nodes [b*256, b*256+256). histg layout: [z*nbkt + b].

__global__ void histA_k(const int* __restrict__ dst, int* __restrict__ histg,
                        int E, int nbkt, int chunk) {
    __shared__ int h[256];
    int tid = threadIdx.x, z = blockIdx.x;
    h[tid] = 0;
    __syncthreads();
    int e0 = z * chunk, e1 = min(E, e0 + chunk);
    for (int e = e0 + tid; e < e1; e += BLK) atomicAdd(&h[dst[e] >> 8], 1);
    __syncthreads();
    if (tid < nbkt) histg[z * nbkt + tid] = h[tid];
}

// Per-bucket exclusive scan over the 256 z-chunks (196 parallel blocks) and
// per-bucket totals.
__global__ void blk_scan2_k(int* __restrict__ histg, int* __restrict__ bsum, int nbkt) {
    __shared__ int s[BLK];
    int t = threadIdx.x, b = blockIdx.x;
    int v = histg[t * nbkt + b];
    s[t] = v;
    __syncthreads();
    for (int o = 1; o < BLK; o <<= 1) {
        int tv = (t >= o) ? s[t - o] : 0;
        __syncthreads();
        s[t] += tv;
        __syncthreads();
    }
    histg[t * nbkt + b] = s[t] - v;            // exclusive, no base yet
    if (t == BLK - 1) bsum[b] = s[t];          // bucket total
}

// Tiny single block: scan 196 bucket totals (LDS-only) + sentinel/stat inits.
__global__ void scan_base_k(const int* __restrict__ bsum, int* __restrict__ bucket_base,
                            int nbkt, int E, int* __restrict__ gs, int* __restrict__ ge,
                            int G, float* __restrict__ bnstats) {
    __shared__ int s[BLK];
    int t = threadIdx.x;
    int v = (t < nbkt) ? bsum[t] : 0;
    s[t] = v;
    __syncthreads();
    for (int o = 1; o < BLK; o <<= 1) {
        int tv = (t >= o) ? s[t - o] : 0;
        __syncthreads();
        s[t] += tv;
        __syncthreads();
    }
    if (t < nbkt) bucket_base[t] = s[t] - v;
    if (t == 0) bucket_base[nbkt] = E;
    for (int i = t; i < G; i += BLK) { gs[i] = 0x7fffffff; ge[i] = -1; }
    for (int i = t; i < 4 * NSH * 256; i += BLK) bnstats[i] = 0.f;
}

__global__ void scatterA_k(const int* __restrict__ src, const int* __restrict__ dst,
                           const int* __restrict__ histg, const int* __restrict__ bucket_base,
                           unsigned* __restrict__ ebkt, int E, int nbkt, int chunk) {
    __shared__ int cur[256];
    int tid = threadIdx.x, z = blockIdx.x;
    if (tid < nbkt) cur[tid] = histg[z * nbkt + tid] + bucket_base[tid];
    __syncthreads();
    int e0 = z * chunk, e1 = min(E, e0 + chunk);
    for (int e = e0 + tid; e < e1; e += BLK) {
        int d = dst[e];
        int b = d >> 8;
        int pos = atomicAdd(&cur[b], 1);
        ebkt[pos] = ((unsigned)(d & 255) << 16) | (unsigned)src[e];
    }
}

// B: per-bucket CSR finalize (degrees->scan->self-loop->fill) + graph ranges.
__global__ void csrB_k(const unsigned* __restrict__ ebkt, const int* __restrict__ bucket_base,
                       int* __restrict__ off, unsigned short* __restrict__ csr,
                       const int* __restrict__ batch, int* __restrict__ gs,
                       int* __restrict__ ge, int N, int E, int nbkt) {
    __shared__ int dg[256];
    __shared__ int sc[256];
    int t = threadIdx.x, b = blockIdx.x;
    int n0 = b << 8;
    int cnt = min(256, N - n0);
    dg[t] = (t < cnt) ? 1 : 0;                     // self-loop
    __syncthreads();
    int e0 = bucket_base[b], e1 = bucket_base[b + 1];
    for (int e = e0 + t; e < e1; e += BLK) atomicAdd(&dg[ebkt[e] >> 16], 1);
    __syncthreads();
    int d = dg[t];
    sc[t] = d;
    __syncthreads();
    for (int o = 1; o < BLK; o <<= 1) {
        int tv = (t >= o) ? sc[t - o] : 0;
        __syncthreads();
        sc[t] += tv;
        __syncthreads();
    }
    int loff = sc[t] - d;                          // exclusive
    int csrbase = e0 + n0;                         // n0 self-loops precede bucket
    if (t < cnt) {
        off[n0 + t] = csrbase + loff;
        csr[csrbase + loff] = (unsigned short)(n0 + t);   // self-loop slot
        dg[t] = loff + 1;                          // cursor
    }
    if (b == nbkt - 1 && t == 0) off[N] = E + N;
    // graph ranges (batch sorted): boundary detection, this grid covers N.
    int n = n0 + t;
    if (n < N) {
        int bb = batch[n];
        if (n == 0) gs[bb] = 0;
        else {
            int pb = batch[n - 1];
            if (pb != bb) { gs[bb] = n; ge[pb] = n - 1; }
        }
        if (n == N - 1) ge[bb] = N - 1;
    }
    __syncthreads();
    for (int e = e0 + t; e < e1; e += BLK) {
        unsigned w = ebkt[e];
        int pos = atomicAdd(&dg[w >> 16], 1);
        csr[csrbase + pos] = (unsigned short)(w & 0xffff);
    }
}

// ---------------- self-contained MFMA GEMM (prep fused in prologue) -----------
// Single-y grid: A fragments loaded ONCE per block, reused across all NOUT/16
// column groups. BN stats arrive as NSH shadow copies (summed here).
template <int K, int NOUT, bool AFP32, bool HASBN>
__launch_bounds__(256)
__global__ void gemm_fused(const void* __restrict__ av, const float* __restrict__ W,
                           const float* __restrict__ a_s, const float* __restrict__ a_d,
                           const float* __restrict__ bnst, const float* __restrict__ g_prev,
                           const float* __restrict__ be_prev, float invN,
                           unsigned short* __restrict__ hb,
                           float* __restrict__ asrc, float* __restrict__ adst, int N) {
    constexpr int KF = K / 32;
    constexpr int NY = NOUT / 16;
    __shared__ float s_sca[K], s_scc[K], s_rs[K], s_rd[K], s_bd[2];
    int tid = threadIdx.x;
    if (tid < K) {
        float a = 1.f, c = 0.f;
        if (HASBN) {
            float su = 0.f, sq = 0.f;
#pragma unroll
            for (int s = 0; s < NSH; ++s) {
                su += bnst[s * 256 + tid];
                sq += bnst[s * 256 + 128 + tid];
            }
            float mu = su * invN;
            float var = sq * invN - mu * mu;
            a = g_prev[tid] * rsqrtf(var + 1e-5f);
            c = be_prev[tid] - mu * a;
        }
        s_sca[tid] = a; s_scc[tid] = c;
    }
    __syncthreads();
    {   // attention-dot vectors
        if (tid < K) {
            const float* wr = W + (long)tid * NOUT;
            float rs = 0.f, rd = 0.f;
            for (int f = 0; f < NOUT; ++f) {
                float w = wr[f];
                rs += w * a_s[f];
                rd += w * a_d[f];
            }
            s_rs[tid] = rs; s_rd[tid] = rd;
        }
        __syncthreads();
        if (tid < 2) {
            const float* r = tid ? s_rd : s_rs;
            float b = 0.f;
            for (int k = 0; k < K; ++k) b += s_scc[k] * r[k];
            s_bd[tid] = b;
        }
        __syncthreads();
    }

    int wave = tid >> 6;
    int lane = tid & 63;
    int quad = lane >> 4;
    int r16 = lane & 15;
    int blockbase = blockIdx.x * 128;

    // ---- A fragments: load once, reuse for all column groups ----
    short8 afr[2][KF];
    bool valid[2];
#pragma unroll
    for (int rt = 0; rt < 2; ++rt) {
        int tilebase = blockbase + wave * 32 + rt * 16;
        valid[rt] = tilebase < N;
        if (!valid[rt]) continue;                       // wave-uniform
        int arow = min(tilebase + r16, N - 1);
        if (AFP32) {
            const float* xr = (const float*)av + (long)arow * K;
#pragma unroll
            for (int kk = 0; kk < KF; ++kk) {
                float4 x0 = *(const float4*)(xr + kk * 32 + quad * 8);
                float4 x1 = *(const float4*)(xr + kk * 32 + quad * 8 + 4);
                short8 a;
                a[0] = (short)f2bf(x0.x); a[1] = (short)f2bf(x0.y);
                a[2] = (short)f2bf(x0.z); a[3] = (short)f2bf(x0.w);
                a[4] = (short)f2bf(x1.x); a[5] = (short)f2bf(x1.y);
                a[6] = (short)f2bf(x1.z); a[7] = (short)f2bf(x1.w);
                afr[rt][kk] = a;
            }
        } else {
            const unsigned short* hr = (const unsigned short*)av + (long)arow * K;
#pragma unroll
            for (int kk = 0; kk < KF; ++kk)
                afr[rt][kk] = *(const short8*)(hr + kk * 32 + quad * 8);
        }
        // per-row attention dots (raw A scaled by BN coeffs)
        float ds = 0.f, dd = 0.f;
#pragma unroll
        for (int kk = 0; kk < KF; ++kk) {
            int kb = kk * 32 + quad * 8;
#pragma unroll
            for (int j = 0; j < 8; ++j) {
                int k = kb + j;
                float a = bf2f((unsigned short)afr[rt][kk][j]) * s_sca[k];
                ds += a * s_rs[k];
                dd += a * s_rd[k];
            }
        }
        ds += __shfl_xor(ds, 16, 64); ds += __shfl_xor(ds, 32, 64);
        dd += __shfl_xor(dd, 16, 64); dd += __shfl_xor(dd, 32, 64);
        int drow = tilebase + r16;
        if (quad == 0 && drow < N) {
            asrc[drow] = ds + s_bd[0];
            adst[drow] = dd + s_bd[1];
        }
    }

    // ---- column-group loop: build B fragment (BN-scaled), MFMA, store ----
#pragma unroll
    for (int y = 0; y < NY; ++y) {
        int col = y * 16 + r16;
        short8 bfr[KF];
        float biasp = 0.f;
#pragma unroll
        for (int kk = 0; kk < KF; ++kk) {
            short8 b;
#pragma unroll
            for (int j = 0; j < 8; ++j) {
                int k = kk * 32 + quad * 8 + j;
                float w = W[(long)k * NOUT + col];
                b[j] = (short)f2bf(s_sca[k] * w);
                biasp += s_scc[k] * w;
            }
            bfr[kk] = b;
        }
        biasp += __shfl_xor(biasp, 16, 64);
        biasp += __shfl_xor(biasp, 32, 64);

#pragma unroll
        for (int rt = 0; rt < 2; ++rt) {
            if (!valid[rt]) continue;                   // wave-uniform
            int tilebase = blockbase + wave * 32 + rt * 16;
            floatx4 acc = {0.f, 0.f, 0.f, 0.f};
#pragma unroll
            for (int kk = 0; kk < KF; ++kk)
                acc = __builtin_amdgcn_mfma_f32_16x16x32_bf16(afr[rt][kk], bfr[kk], acc, 0, 0, 0);
#pragma unroll
            for (int rr = 0; rr < 4; ++rr) {
                int srow = tilebase + quad * 4 + rr;
                if (srow < N) hb[(long)srow * NOUT + col] = f2bf(acc[rr] + biasp);
            }
        }
    }
}

// ---------------- fused softmax + gather + bias + leaky(0.01) + BN stats -----
// Single-pass online softmax (exp without max-subtraction; |e| is O(1)).
// FPL = features per lane. BN statistics are computed in the epilogue from the
// final register values: butterfly-shfl across node-groups within each wave,
// wave-leader LDS atomics, then one per-block flush into NSH global shadow
// copies -> the separate 28.8MB stats pass family is eliminated.
template <int DOUT, int FPL>
__global__ void gather_fused(const int* __restrict__ off,
                             const unsigned short* __restrict__ csr,
                             const float* __restrict__ asrc, const float* __restrict__ adst,
                             const unsigned short* __restrict__ hb,
                             const float* __restrict__ b,
                             unsigned short* __restrict__ out,
                             float* __restrict__ bn, int N) {
    constexpr int TPN = DOUT / FPL;
    constexpr int NV = FPL / 8;
    __shared__ float sst[2 * DOUT];
    int tid = threadIdx.x;
    if (tid < 2 * DOUT) sst[tid] = 0.f;
    __syncthreads();

    int t = blockIdx.x * blockDim.x + tid;
    int d = t / TPN;
    int l = t % TPN;
    bool active = d < N;
    int lane = tid & 63;

    int p0 = 0, p1 = 0;
    float ad = 0.f;
    if (active) { p0 = off[d]; p1 = off[d + 1]; ad = adst[d]; }
    const int f0 = l * FPL;

    float acc[FPL];
#pragma unroll
    for (int i = 0; i < FPL; ++i) acc[i] = 0.f;
    float sum = 0.f;

#pragma unroll 2
    for (int p = p0; p < p1; ++p) {
        int s = csr[p];                           // broadcast across group
        float e = asrc[s] + ad;                   // broadcast load
        e = e > 0.f ? e : 0.2f * e;               // leaky_relu(0.2)
        float w = __expf(e);
        sum += w;
        const unsigned short* hr = hb + (long)s * DOUT + f0;
#pragma unroll
        for (int v = 0; v < NV; ++v) {
            const uint4 hv = *(const uint4*)(hr + v * 8);
            acc[v * 8 + 0] += w * bf2f((unsigned short)(hv.x & 0xffff));
            acc[v * 8 + 1] += w * bf2f((unsigned short)(hv.x >> 16));
            acc[v * 8 + 2] += w * bf2f((unsigned short)(hv.y & 0xffff));
            acc[v * 8 + 3] += w * bf2f((unsigned short)(hv.y >> 16));
            acc[v * 8 + 4] += w * bf2f((unsigned short)(hv.z & 0xffff));
            acc[v * 8 + 5] += w * bf2f((unsigned short)(hv.z >> 16));
            acc[v * 8 + 6] += w * bf2f((unsigned short)(hv.w & 0xffff));
            acc[v * 8 + 7] += w * bf2f((unsigned short)(hv.w >> 16));
        }
    }
    float inv = active ? (1.f / sum) : 0.f;       // self-loop guarantees sum > 0

    // final values (post bias+leaky) into acc[], pack + store
#pragma unroll
    for (int v = 0; v < NV; ++v) {
        float4 b0 = *(const float4*)(b + f0 + v * 8);
        float4 b1 = *(const float4*)(b + f0 + v * 8 + 4);
        float bbv[8] = {b0.x, b0.y, b0.z, b0.w, b1.x, b1.y, b1.z, b1.w};
        unsigned pk[4];
#pragma unroll
        for (int i = 0; i < 4; ++i) {
            float v0 = acc[v * 8 + 2 * i] * inv + bbv[2 * i];
            float v1 = acc[v * 8 + 2 * i + 1] * inv + bbv[2 * i + 1];
            v0 = v0 > 0.f ? v0 : 0.01f * v0;      // leaky_relu(0.01)
            v1 = v1 > 0.f ? v1 : 0.01f * v1;
            if (!active) { v0 = 0.f; v1 = 0.f; }  // no stat contribution
            acc[v * 8 + 2 * i] = v0;
            acc[v * 8 + 2 * i + 1] = v1;
            pk[i] = (unsigned)f2bf(v0) | ((unsigned)f2bf(v1) << 16);
        }
        if (active)
            *(uint4*)(out + (long)d * DOUT + f0 + v * 8) = uint4{pk[0], pk[1], pk[2], pk[3]};
    }

    // BN stats: butterfly across node-groups (same l) within the wave
#pragma unroll
    for (int i = 0; i < FPL; ++i) {
        float s = acc[i];
        float q = s * s;
#pragma unroll
        for (int o = TPN; o < 64; o <<= 1) {
            s += __shfl_xor(s, o, 64);
            q += __shfl_xor(q, o, 64);
        }
        if (lane < TPN) {
            atomicAdd(&sst[f0 + i], s);
            atomicAdd(&sst[DOUT + f0 + i], q);
        }
    }
    __syncthreads();
    if (tid < 2 * DOUT) {
        float* base = bn + (blockIdx.x & (NSH - 1)) * 256;
        int idx = (tid < DOUT) ? tid : (128 + tid - DOUT);
        atomicAdd(&base[idx], sst[tid]);
    }
}

// ---------------- pool (with inline final BN) + MLP head, fused --------------
__global__ void pool_head_k(const unsigned short* __restrict__ h, const int* __restrict__ gs,
                            const int* __restrict__ ge, const float* __restrict__ bnst,
                            const float* __restrict__ g4, const float* __restrict__ be4,
                            float invN, const float* __restrict__ Wf,
                            const float* __restrict__ bf, const float* __restrict__ Wc,
                            const float* __restrict__ bc, float* __restrict__ out) {
    int g = blockIdx.x;
    int t = threadIdx.x;                          // 256 threads
    int f = t & 63, sub = t >> 6;                 // 4 row-subsets
    __shared__ float pp[4][64];
    __shared__ float p[64];
    __shared__ float z[32];
    int s0 = gs[g], s1 = ge[g];
    float acc = 0.f;
    if (s0 <= s1)
        for (int n = s0 + sub; n <= s1; n += 4) acc += bf2f(h[(long)n * 64 + f]);
    pp[sub][f] = acc;
    __syncthreads();
    if (t < 64) {
        float su = 0.f, sq = 0.f;
#pragma unroll
        for (int s = 0; s < NSH; ++s) {
            su += bnst[s * 256 + t];
            sq += bnst[s * 256 + 128 + t];
        }
        float mu = su * invN;
        float var = sq * invN - mu * mu;
        float a = g4[t] * rsqrtf(var + 1e-5f);
        float c = be4[t] - mu * a;
        float cnt = (s0 <= s1) ? (float)(s1 - s0 + 1) : 0.f;
        p[t] = a * (pp[0][t] + pp[1][t] + pp[2][t] + pp[3][t]) + cnt * c;
    }
    __syncthreads();
    if (t < 32) {
        float zacc = bf[t];
#pragma unroll
        for (int ff = 0; ff < 64; ++ff) zacc += p[ff] * Wf[ff * 32 + t];
        z[t] = zacc > 0.f ? zacc : 0.01f * zacc;
    }
    __syncthreads();
    if (t < 8) {
        float oacc = bc[t];
#pragma unroll
        for (int o = 0; o < 32; ++o) oacc += z[o] * Wc[o * 8 + t];
        out[(long)g * 8 + t] = 1.f / (1.f + __expf(-oacc));
    }
}

extern "C" void kernel_launch(void* const* d_in, const int* in_sizes, int n_in,
                              void* d_out, int out_size, void* d_ws, size_t ws_size,
                              hipStream_t stream) {
    const float* x   = (const float*)d_in[0];
    const int* ei    = (const int*)d_in[1];
    const int* batch = (const int*)d_in[2];
    const int N  = in_sizes[2];
    const int E  = in_sizes[1] / 2;
    const int ET = E + N;
    const int G  = out_size / 8;
    const int* src = ei;
    const int* dst = ei + E;

    const float *W[4], *as_[4], *ad_[4], *bb[4], *gg[4], *be_[4];
    for (int i = 0; i < 4; ++i) {
        W[i]   = (const float*)d_in[3 + 6 * i];
        as_[i] = (const float*)d_in[4 + 6 * i];
        ad_[i] = (const float*)d_in[5 + 6 * i];
        bb[i]  = (const float*)d_in[6 + 6 * i];
        gg[i]  = (const float*)d_in[7 + 6 * i];
        be_[i] = (const float*)d_in[8 + 6 * i];
    }
    const float* Wf = (const float*)d_in[27];
    const float* bfp = (const float*)d_in[28];
    const float* Wc = (const float*)d_in[29];
    const float* bc = (const float*)d_in[30];

    float* ws = (float*)d_ws;
    long off_ = 0;
    auto alloc = [&](long nelem) { float* p = ws + off_; off_ += (nelem + 3) & ~3L; return p; };
    unsigned short* h2a = (unsigned short*)alloc((long)N * 64);  // N x 128 bf16
    unsigned short* h2b = (unsigned short*)alloc((long)N * 64);
    unsigned short* hb  = (unsigned short*)alloc((long)N * 64);
    float* asrc     = alloc(N);
    float* adst     = alloc(N);
    float* bnstats  = alloc((long)4 * NSH * 256); // per-layer: NSH shadows x (sum[128]|sq[128])
    unsigned* ebkt  = (unsigned*)alloc(E);
    int* histg      = (int*)alloc((long)NBLKA * 256);
    int* bucket_base = (int*)alloc(260);
    int* bsum       = (int*)alloc(256);
    int* off        = (int*)alloc(N + 1);
    unsigned short* csr = (unsigned short*)alloc(ET / 2 + 2);
    int* gs         = (int*)alloc(G);
    int* ge         = (int*)alloc(G);
    (void)ws_size; (void)n_in;

    const int nbkt = cdiv(N, 256);          // 196
    const int chunk = cdiv(E, NBLKA);
    const float invN = 1.f / (float)N;

    // ---- CSR build (bucket sort, no global atomics) + graph ranges ----
    histA_k<<<NBLKA, BLK, 0, stream>>>(dst, histg, E, nbkt, chunk);
    blk_scan2_k<<<nbkt, BLK, 0, stream>>>(histg, bsum, nbkt);
    scan_base_k<<<1, BLK, 0, stream>>>(bsum, bucket_base, nbkt, E, gs, ge, G, bnstats);
    scatterA_k<<<NBLKA, BLK, 0, stream>>>(src, dst, histg, bucket_base, ebkt, E, nbkt, chunk);
    csrB_k<<<nbkt, BLK, 0, stream>>>(ebkt, bucket_base, off, csr, batch, gs, ge, N, E, nbkt);

#define LAYER(i, DIN, DOUT, FPL, AFP32, HASBN, INP, OUTP, BNPREV, GPREV, BEPREV)          \
    do {                                                                                  \
        gemm_fused<DIN, DOUT, AFP32, HASBN>                                               \
            <<<cdiv(N, 128), 256, 0, stream>>>(                                           \
                INP, W[i], as_[i], ad_[i], BNPREV, GPREV, BEPREV, invN,                   \
                hb, asrc, adst, N);                                                       \
        gather_fused<DOUT, FPL><<<cdiv((long)N * (DOUT / FPL), BLK), BLK, 0, stream>>>(   \
            off, csr, asrc, adst, hb, bb[i], OUTP, bnstats + (long)i * NSH * 256, N);     \
    } while (0)

    LAYER(0, 128, 32, 8,  true,  false, x,   h2b, bnstats,                 gg[0], be_[0]);
    LAYER(1, 32,  64, 16, false, true,  h2b, h2a, bnstats + 0L * NSH * 256, gg[0], be_[0]);
    LAYER(2, 64, 128, 16, false, true,  h2a, h2b, bnstats + 1L * NSH * 256, gg[1], be_[1]);
    LAYER(3, 128, 64, 16, false, true,  h2b, h2a, bnstats + 2L * NSH * 256, gg[2], be_[2]);
#undef LAYER

    pool_head_k<<<G, 256, 0, stream>>>(h2a, gs, ge, bnstats + 3L * NSH * 256, gg[3], be_[3],
                                       invN, Wf, bfp, Wc, bc, (float*)d_out);
}